// Round 6
// baseline (145.553 us; speedup 1.0000x reference)
//
#include <hip/hip_runtime.h>

typedef unsigned short u16;
typedef unsigned int u32;

typedef __bf16 bf16x8 __attribute__((ext_vector_type(8)));
typedef float floatx4 __attribute__((ext_vector_type(4)));

// ---- helpers ----------------------------------------------------------------

__device__ __forceinline__ u32 f2bf(float f) {
    // round-to-nearest-even fp32 -> bf16 (bit pattern in low 16)
    u32 u = __builtin_bit_cast(u32, f);
    return (u + 0x7fffu + ((u >> 16) & 1u)) >> 16;
}

__device__ __forceinline__ float quant_w(float x) {
    // WAGE Quantize.W, BITS_W=2: clip to [-0.5,0.5], round to grid step 0.5 (RNE)
    float xc = fminf(fmaxf(x, -0.5f), 0.5f);
    return rintf(xc * 2.0f) * 0.5f;
}

__device__ __forceinline__ void gload_lds16(const u16* g, u16* l) {
    __builtin_amdgcn_global_load_lds(
        (const __attribute__((address_space(1))) void*)g,
        (__attribute__((address_space(3))) void*)l,
        16, 0, 0);
}

// ---- kernel 1: cast A fp32 -> bf16 (8 floats / thread) ----------------------

__global__ __launch_bounds__(256) void cast_a_kernel(const float4* __restrict__ in,
                                                     uint4* __restrict__ out) {
    int t = blockIdx.x * 256 + threadIdx.x;
    float4 a = in[2 * t];
    float4 b = in[2 * t + 1];
    uint4 o;
    o.x = f2bf(a.x) | (f2bf(a.y) << 16);
    o.y = f2bf(a.z) | (f2bf(a.w) << 16);
    o.z = f2bf(b.x) | (f2bf(b.y) << 16);
    o.w = f2bf(b.z) | (f2bf(b.w) << 16);
    out[t] = o;
}

// ---- kernel 2: quantize + transpose W[k][n] -> Bt[n][k] bf16 ----------------

__global__ __launch_bounds__(256) void quant_transpose_kernel(const float* __restrict__ W,
                                                              u16* __restrict__ Bt) {
    __shared__ u16 tile[32][33];  // +1 pad: no bank conflicts
    const int KN = 1024;
    int tx = threadIdx.x;  // 0..31
    int ty = threadIdx.y;  // 0..7
    int k0 = blockIdx.y * 32;
    int n0 = blockIdx.x * 32;
#pragma unroll
    for (int i = 0; i < 4; i++) {
        int kl = ty + i * 8;
        float x = W[(k0 + kl) * KN + n0 + tx];
        tile[kl][tx] = (u16)f2bf(quant_w(x));
    }
    __syncthreads();
#pragma unroll
    for (int i = 0; i < 4; i++) {
        int nl = ty + i * 8;
        Bt[(n0 + nl) * KN + k0 + tx] = tile[tx][nl];
    }
}

// ---- kernel 3: 256x256 4-region pipelined GEMM  C = A(bf16) * Bt^T ----------
// 512 thr = 8 waves (2M x 4N), per-wave 128x64 out, BK=64, LDS 128 KB (2 dbuf).
// R5 lesson: pre-barrier lgkmcnt(0) drains serialized every region (MfmaUtil
// 29%). R6: NO explicit lgkm drains. WAR safety comes from the consumption
// argument: every ds_read is consumed by an MFMA in the NEXT region, and MFMA
// issue forces the compiler's counted lgkm wait -> reads are drained before
// that wave can arrive at the following barrier. Hence a stage issued >=2
// barriers after a slot's last read can never overwrite un-drained reads.
//
//   G0: M3(t-1)[af1 x bf1] || read af0,bf0(t) || stage B(t+1)   | bar
//   G1: M0(t)  [af0 x bf0] || read af1(t)                       | bar
//   G2: M1(t)  [af1 x bf0] || read bf1(t)                       | bar
//   G3: M2(t)  [af0 x bf1] || stage A(t+2) ; vmcnt(4)           | bar
//
// WAR: A-slot last read af1@G1(t), consumed M1@G2(t) -> drained before each
//   wave's G2-end barrier -> A-stage @G3(t) safe. B-slot last read bf1@G2(t),
//   consumed M2@G3(t) -> drained before G3-end barrier -> B-stage @G0(t+1)
//   safe (targets buffer (t+1)&1, whose bf1 reads were in tile t-1).
// RAW (vmcnt; 4 A-loads + 4 B-loads per tile; in-order retire):
//   G3(t) queue = [A(t+1)@G3(t-1), B(t+1)@G0(t), A(t+2)@G3(t)] = 12;
//   vmcnt(4) drains A(t+1)+B(t+1) (both read at G0/G1(t+1)), keeps A(t+2)
//   in flight. Issue->use distance = 4 regions >> HBM latency. t=14: vmcnt(0).
// Prologue: stage A(0),B(0),A(1); vmcnt(4) lands tile 0, A(1) stays in flight.
// Per-acc MFMA order identical to R3/R5 -> bitwise-equal C.

__global__ __launch_bounds__(512, 2) void gemm_4region_kernel(const u16* __restrict__ A,
                                                              const u16* __restrict__ Bt,
                                                              float* __restrict__ C) {
    const int K = 1024;
    const int N = 1024;

    __shared__ alignas(16) u16 As[2 * 2 * 128 * 64];  // 64 KB
    __shared__ alignas(16) u16 Bs[2 * 2 * 128 * 64];  // 64 KB

    const int tid = threadIdx.x;
    const int lane = tid & 63;
    const int wid = tid >> 6;
    const int wm = wid >> 2;      // M half (128 rows)
    const int wn = wid & 3;       // N quarter (64 cols)
    const int frow = lane & 15;
    const int fkc = lane >> 4;
    const int rsw = frow & 7;
    const int mbase = blockIdx.x * 256;
    const int nbase = blockIdx.y * 256;

    const int sr = tid >> 3;
    const int gc = (tid & 7) ^ (sr & 7);

    const u16* Abase = &A[(size_t)(mbase + sr) * K + gc * 8];
    const u16* Bbase = &Bt[(size_t)(nbase + sr) * K + gc * 8];

    floatx4 acc[8][4] = {};
    bf16x8 af0[4][2], af1[4][2], bf0[2][2], bf1[2][2];

    // stage unit q of tile tau. q: 0=B-half0, 1=B-half1, 2=A-half0, 3=A-half1
    auto stage = [&](int tau, int q) {
        const int hf = q & 1;
        const int isA = q >> 1;
        const u16* gb = isA ? Abase : Bbase;
        u16* lb = isA ? As : Bs;
        const size_t goff = (size_t)(hf * 128) * K + (size_t)tau * 64;
        u16* dst = &lb[(((tau & 1) * 2 + hf) * 8192) + tid * 8];
        gload_lds16(gb + goff, dst);
        gload_lds16(gb + goff + (size_t)64 * K, dst + 4096);
    };

#define VMC(n)  asm volatile("s_waitcnt vmcnt(" #n ")" ::: "memory")
#define BAR()                          \
    __builtin_amdgcn_sched_barrier(0); \
    __builtin_amdgcn_s_barrier();      \
    __builtin_amdgcn_sched_barrier(0)

#define READ_AF0(b)                                                                  \
    _Pragma("unroll") for (int mf = 0; mf < 4; mf++)                                 \
        _Pragma("unroll") for (int s = 0; s < 2; s++)                                \
            af0[mf][s] = *(const bf16x8*)&As[(((b)*2 + wm) * 128 + mf * 16 + frow) * 64 + \
                                             (((s * 4 + fkc) ^ rsw) * 8)]
#define READ_AF1(b)                                                                  \
    _Pragma("unroll") for (int mf = 0; mf < 4; mf++)                                 \
        _Pragma("unroll") for (int s = 0; s < 2; s++)                                \
            af1[mf][s] = *(const bf16x8*)&As[(((b)*2 + wm) * 128 + 64 + mf * 16 + frow) * 64 + \
                                             (((s * 4 + fkc) ^ rsw) * 8)]
#define READ_BF0(b)                                                                  \
    _Pragma("unroll") for (int nf = 0; nf < 2; nf++)                                 \
        _Pragma("unroll") for (int s = 0; s < 2; s++)                                \
            bf0[nf][s] = *(const bf16x8*)&Bs[(((b)*2 + (wn >> 1)) * 128 + (wn & 1) * 64 + nf * 16 + frow) * 64 + \
                                             (((s * 4 + fkc) ^ rsw) * 8)]
#define READ_BF1(b)                                                                  \
    _Pragma("unroll") for (int nf = 0; nf < 2; nf++)                                 \
        _Pragma("unroll") for (int s = 0; s < 2; s++)                                \
            bf1[nf][s] = *(const bf16x8*)&Bs[(((b)*2 + (wn >> 1)) * 128 + (wn & 1) * 64 + 32 + nf * 16 + frow) * 64 + \
                                             (((s * 4 + fkc) ^ rsw) * 8)]
#define MFMA_CL(af, bf, mo, no)                                                      \
    __builtin_amdgcn_s_setprio(1);                                                   \
    _Pragma("unroll") for (int mf = 0; mf < 4; mf++)                                 \
        _Pragma("unroll") for (int nf = 0; nf < 2; nf++)                             \
            _Pragma("unroll") for (int s = 0; s < 2; s++)                            \
                acc[(mo) + mf][(no) + nf] = __builtin_amdgcn_mfma_f32_16x16x32_bf16( \
                    af[mf][s], bf[nf][s], acc[(mo) + mf][(no) + nf], 0, 0, 0);       \
    __builtin_amdgcn_s_setprio(0)

    // ---- prologue: A(0),B(0) landed; A(1) left in flight (4 ops) ----
    stage(0, 2); stage(0, 3); stage(0, 0); stage(0, 1);
    stage(1, 2); stage(1, 3);
    VMC(4);
    BAR();

    for (int t = 0; t < 16; t++) {
        const int b = t & 1;

        // ---- G0: M3(t-1) || read af0,bf0(t) || stage B(t+1) ----
        if (t > 0) { MFMA_CL(af1, bf1, 4, 2); }
        READ_AF0(b);
        READ_BF0(b);
        if (t <= 14) { stage(t + 1, 0); stage(t + 1, 1); }
        BAR();

        // ---- G1: M0(t) || read af1(t) ----
        MFMA_CL(af0, bf0, 0, 0);
        READ_AF1(b);
        BAR();

        // ---- G2: M1(t) || read bf1(t) ----
        MFMA_CL(af1, bf0, 4, 0);
        READ_BF1(b);
        BAR();

        // ---- G3: M2(t) || stage A(t+2) ; counted vmcnt ----
        MFMA_CL(af0, bf1, 0, 2);
        if (t <= 13) {
            stage(t + 2, 2); stage(t + 2, 3);
            VMC(4);
        } else if (t == 14) {
            VMC(0);
        }
        BAR();
    }

    // ---- epilogue MFMA: M3(15) ----
    MFMA_CL(af1, bf1, 4, 2);

#undef VMC
#undef BAR
#undef READ_AF0
#undef READ_AF1
#undef READ_BF0
#undef READ_BF1
#undef MFMA_CL

    // epilogue: C/D layout col = lane&15, row = (lane>>4)*4 + reg
    const int crow = (lane >> 4) * 4;
    const int ccol = lane & 15;
#pragma unroll
    for (int i = 0; i < 8; i++) {
#pragma unroll
        for (int j = 0; j < 4; j++) {
            float* cp = &C[(size_t)(mbase + wm * 128 + i * 16 + crow) * N +
                           nbase + wn * 64 + j * 16 + ccol];
#pragma unroll
            for (int r = 0; r < 4; r++) cp[r * N] = acc[i][j][r];
        }
    }
}

// ---- launch -----------------------------------------------------------------

extern "C" void kernel_launch(void* const* d_in, const int* in_sizes, int n_in,
                              void* d_out, int out_size, void* d_ws, size_t ws_size,
                              hipStream_t stream) {
    const float* A = (const float*)d_in[0];   // 16384 x 1024 fp32
    const float* W = (const float*)d_in[1];   // 1024 x 1024 fp32
    float* C = (float*)d_out;                 // 16384 x 1024 fp32

    u16* Abf = (u16*)d_ws;                                   // 32 MB bf16 A
    u16* Btq = (u16*)((char*)d_ws + (size_t)33554432);       // 2 MB quantized W^T

    cast_a_kernel<<<8192, 256, 0, stream>>>((const float4*)A, (uint4*)Abf);
    quant_transpose_kernel<<<dim3(32, 32), dim3(32, 8), 0, stream>>>(W, Btq);
    gemm_4region_kernel<<<dim3(64, 4), 512, 0, stream>>>(Abf, Btq, C);
}